// Round 6
// baseline (17294.569 us; speedup 1.0000x reference)
//
#include <hip/hip_runtime.h>
#include <math.h>

// Sizes: B=32, N=128, EMB=1024, HID=512, L=2, NCLS=7, IN_DIM=3072, TOK=4096
// Scan design: column-ownership. 4 pods x 64 WGs x 8 batches. WG w owns
// h-cols [8w,8w+8) => 48 gate cols, 16 V cols, 8 M' cols. Weights L2-resident
// per-WG slices. Cross-WG per step: M broadcast + h broadcast only (stc/ldc).
// Softmax query-term cancels => attention needs only hk history (LDS-local).

#define AGENT __HIP_MEMORY_SCOPE_AGENT

__device__ __forceinline__ float ldc(const float* p) {
    return __hip_atomic_load(p, __ATOMIC_RELAXED, AGENT);
}
__device__ __forceinline__ void stc(float* p, float v) {
    __hip_atomic_store(p, v, __ATOMIC_RELAXED, AGENT);
}

__device__ __forceinline__ void podbar(int* bar, int nwg) {
    __syncthreads();
    if (threadIdx.x == 0) {
        int g = __hip_atomic_load(bar + 1, __ATOMIC_RELAXED, AGENT);
        int v = __hip_atomic_fetch_add(bar, 1, __ATOMIC_RELAXED, AGENT);
        if (v == nwg - 1) {
            __hip_atomic_store(bar, 0, __ATOMIC_RELAXED, AGENT);
            __builtin_amdgcn_s_waitcnt(0);
            __hip_atomic_store(bar + 1, g + 1, __ATOMIC_RELAXED, AGENT);
        } else {
            while (__hip_atomic_load(bar + 1, __ATOMIC_RELAXED, AGENT) == g) {
                __builtin_amdgcn_s_sleep(1);
            }
        }
        __asm__ __volatile__("" ::: "memory");
    }
    __syncthreads();
}

__global__ void init_bar(int* bar) { bar[threadIdx.x] = 0; }

__device__ __forceinline__ float sigf(float x) { return 1.f / (1.f + __expf(-x)); }

// ---------------------------------------------------------------------------
// Generic fp32 GEMM: C = act(A[M,K] @ W[N,K]^T + bias). 64x64 tile.
// ---------------------------------------------------------------------------
__global__ __launch_bounds__(256) void gemm_nt(
    const float* __restrict__ A, const float* __restrict__ W,
    const float* __restrict__ bias, float* __restrict__ C,
    int M, int N, int K, int relu)
{
    __shared__ float As[16][68];
    __shared__ float Ws[16][68];
    const int tid = threadIdx.x;
    const int m0 = blockIdx.x * 64;
    const int n0 = blockIdx.y * 64;
    const int lr = tid >> 2;
    const int lk = (tid & 3) << 2;
    const int tm = (tid & 15) << 2;
    const int tn = (tid >> 4) << 2;
    float acc[4][4] = {};
    const float* Aptr = A + (size_t)(m0 + lr) * K + lk;
    const float* Wptr = W + (size_t)(n0 + lr) * K + lk;
    for (int k0 = 0; k0 < K; k0 += 16) {
        __syncthreads();
        const float4 av = *(const float4*)(Aptr + k0);
        const float4 wv = *(const float4*)(Wptr + k0);
        As[lk + 0][lr] = av.x; As[lk + 1][lr] = av.y;
        As[lk + 2][lr] = av.z; As[lk + 3][lr] = av.w;
        Ws[lk + 0][lr] = wv.x; Ws[lk + 1][lr] = wv.y;
        Ws[lk + 2][lr] = wv.z; Ws[lk + 3][lr] = wv.w;
        __syncthreads();
        #pragma unroll
        for (int kk = 0; kk < 16; ++kk) {
            float a[4], b[4];
            #pragma unroll
            for (int u = 0; u < 4; ++u) { a[u] = As[kk][tm + u]; b[u] = Ws[kk][tn + u]; }
            #pragma unroll
            for (int ii = 0; ii < 4; ++ii)
                #pragma unroll
                for (int jj = 0; jj < 4; ++jj)
                    acc[ii][jj] += a[ii] * b[jj];
        }
    }
    #pragma unroll
    for (int ii = 0; ii < 4; ++ii)
        #pragma unroll
        for (int jj = 0; jj < 4; ++jj) {
            float v = acc[ii][jj] + bias[n0 + tn + jj];
            if (relu) v = fmaxf(v, 0.f);
            C[(size_t)(m0 + tm + ii) * N + n0 + tn + jj] = v;
        }
}

// ---------------------------------------------------------------------------
// mlp0 with fused 5-way concat
// ---------------------------------------------------------------------------
__global__ __launch_bounds__(256) void gemm_cat(
    const float* __restrict__ H0, const float* __restrict__ H1,
    const float* __restrict__ H2, const float* __restrict__ feat,
    const float* __restrict__ lstm, const float* __restrict__ W,
    const float* __restrict__ bias, float* __restrict__ C)
{
    __shared__ float As[16][68];
    __shared__ float Ws[16][68];
    const int tid = threadIdx.x;
    const int m0 = blockIdx.x * 64;
    const int n0 = blockIdx.y * 64;
    const int lr = tid >> 2;
    const int lk = (tid & 3) << 2;
    const int tm = (tid & 15) << 2;
    const int tn = (tid >> 4) << 2;
    float acc[4][4] = {};
    for (int k0 = 0; k0 < 3072; k0 += 16) {
        const float* src; int kloc, Kp;
        if (k0 < 512)       { src = H0;   kloc = k0;        Kp = 512;  }
        else if (k0 < 1024) { src = H1;   kloc = k0 - 512;  Kp = 512;  }
        else if (k0 < 1536) { src = H2;   kloc = k0 - 1024; Kp = 512;  }
        else if (k0 < 2560) { src = feat; kloc = k0 - 1536; Kp = 1024; }
        else                { src = lstm; kloc = k0 - 2560; Kp = 512;  }
        __syncthreads();
        const float4 av = *(const float4*)(src + (size_t)(m0 + lr) * Kp + kloc + lk);
        const float4 wv = *(const float4*)(W + (size_t)(n0 + lr) * 3072 + k0 + lk);
        As[lk + 0][lr] = av.x; As[lk + 1][lr] = av.y;
        As[lk + 2][lr] = av.z; As[lk + 3][lr] = av.w;
        Ws[lk + 0][lr] = wv.x; Ws[lk + 1][lr] = wv.y;
        Ws[lk + 2][lr] = wv.z; Ws[lk + 3][lr] = wv.w;
        __syncthreads();
        #pragma unroll
        for (int kk = 0; kk < 16; ++kk) {
            float a[4], b[4];
            #pragma unroll
            for (int u = 0; u < 4; ++u) { a[u] = As[kk][tm + u]; b[u] = Ws[kk][tn + u]; }
            #pragma unroll
            for (int ii = 0; ii < 4; ++ii)
                #pragma unroll
                for (int jj = 0; jj < 4; ++jj)
                    acc[ii][jj] += a[ii] * b[jj];
        }
    }
    #pragma unroll
    for (int ii = 0; ii < 4; ++ii)
        #pragma unroll
        for (int jj = 0; jj < 4; ++jj) {
            float v = fmaxf(acc[ii][jj] + bias[n0 + tn + jj], 0.f);
            C[(size_t)(m0 + tm + ii) * 512 + n0 + tn + jj] = v;
        }
}

// ---------------------------------------------------------------------------
// One GNN layer scan. Grid 256 = 4 pods x 64 WGs, 8 batches per pod.
// WG w: h-cols J0=8w..J0+8 (48 gate cols, 16 V cols, 8 M' cols).
// Per step: [optional LSTM substep] ph1: stage M, GG slice, gates -> h slice;
// bar; ph2: stage h, hk (redundant per WG, LDS history), V slice (private),
// softmax from hk history (query term cancels), M' slice; bar.
// ---------------------------------------------------------------------------
__global__ __launch_bounds__(256, 1) void scan_layer(
    const float* __restrict__ Hin, float* __restrict__ Hout,
    const float* __restrict__ adj, const float* __restrict__ smk,
    const float* __restrict__ preQc, const float* __restrict__ preQp,
    const float* __restrict__ cWhh, const float* __restrict__ pWih,
    const float* __restrict__ cbhh, const float* __restrict__ pbih,
    const float* __restrict__ attnW,
    const float* __restrict__ Wr0, const float* __restrict__ Wr1,
    float* __restrict__ Mbuf, float* __restrict__ hxch, float* __restrict__ Vh,
    int* __restrict__ bar, const int with_lstm,
    const float* __restrict__ gi, const float* __restrict__ lstm_Whh,
    const float* __restrict__ lstm_bhh, float* __restrict__ lstm_hbuf,
    float* __restrict__ lstm_out)
{
    __shared__ float Ms[16 * 520];   // M/h stage (GNN uses rows 0..7), LSTM h stage (rows 0..15)
    __shared__ float eh[8 * 128];    // hk history per batch
    __shared__ float wsf[8 * 128];   // softmax numerators per step
    __shared__ float gg[8 * 48];     // GG slice
    __shared__ float red[8 * 34];    // reductions
    __shared__ float wkL[512];

    const int wg = blockIdx.x, tid = threadIdx.x;
    const int pod = wg >> 6, w = wg & 63;
    int* pbar = bar + pod * 64;
    const int b0 = pod * 8;
    const int J0 = w * 8;
    const int bq = tid >> 5, u = tid & 31;

    // LSTM slice ids: pod owns rows [32*pod, 32*pod+32); WG: 16 rows x 16 hid
    const int lrowbase = pod * 32 + (w >> 5) * 16;
    const int lhb = w & 31;
    const int lr = tid >> 4, lhh = tid & 15;
    const int lghid = lhb * 16 + lhh;
    float lc = 0.f;

    for (int s = tid; s < 512; s += 256) wkL[s] = attnW[512 + s];

    // zero this pod's M
    if (w < 16) stc(Mbuf + pod * 4096 + w * 256 + tid, 0.f);
    podbar(pbar, 64);

    // GG col assignments: c1 = u (all threads), c2 = u + 32 (u < 16 only)
    const int c1 = u, g1 = c1 >> 3, j1 = J0 + (c1 & 7);
    const float* wrow1 = (g1 < 3) ? cWhh + (size_t)(g1 * 512 + j1) * 512
                                  : pWih + (size_t)((g1 - 3) * 512 + j1) * 512;
    const float bia1 = (g1 < 3) ? cbhh[g1 * 512 + j1] : pbih[(g1 - 3) * 512 + j1];
    const int c2 = u + 32, g2 = c2 >> 3, j2 = J0 + (c2 & 7);   // g2 in {4,5} -> pWih
    const float* wrow2 = pWih + (size_t)((g2 - 3) * 512 + j2) * 512;
    const float bia2 = pbih[(g2 - 3) * 512 + j2];

    for (int i = 0; i < 128; ++i) {
        // ----------------- LSTM substep (first 32 steps, scan0 only) -----
        if (with_lstm && i < 32) {
            const int par = i & 1;
            if (i > 0) {
                const float* hsrc = lstm_hbuf + (size_t)par * 65536;
                for (int s = tid; s < 8192; s += 256)
                    Ms[(s >> 9) * 520 + (s & 511)] =
                        ldc(hsrc + (size_t)(lrowbase + (s >> 9)) * 512 + (s & 511));
            }
            __syncthreads();
            const int lrow = lrowbase + lr;
            const float* gir = gi + ((size_t)i * 128 + lrow) * 2048;
            float s0 = lstm_bhh[lghid] + gir[lghid];
            float s1 = lstm_bhh[512 + lghid] + gir[512 + lghid];
            float s2 = lstm_bhh[1024 + lghid] + gir[1024 + lghid];
            float s3 = lstm_bhh[1536 + lghid] + gir[1536 + lghid];
            if (i > 0) {
                const float* hr = Ms + lr * 520;
                const float* W0 = lstm_Whh + (size_t)lghid * 512;
                const float* W1 = lstm_Whh + (size_t)(512 + lghid) * 512;
                const float* W2 = lstm_Whh + (size_t)(1024 + lghid) * 512;
                const float* W3 = lstm_Whh + (size_t)(1536 + lghid) * 512;
                for (int k = 0; k < 512; k += 4) {
                    const float4 h4 = *(const float4*)(hr + k);
                    const float4 a4 = *(const float4*)(W0 + k);
                    const float4 b4 = *(const float4*)(W1 + k);
                    const float4 c4 = *(const float4*)(W2 + k);
                    const float4 d4 = *(const float4*)(W3 + k);
                    s0 += h4.x*a4.x + h4.y*a4.y + h4.z*a4.z + h4.w*a4.w;
                    s1 += h4.x*b4.x + h4.y*b4.y + h4.z*b4.z + h4.w*b4.w;
                    s2 += h4.x*c4.x + h4.y*c4.y + h4.z*c4.z + h4.w*c4.w;
                    s3 += h4.x*d4.x + h4.y*d4.y + h4.z*d4.z + h4.w*d4.w;
                }
            }
            lc = sigf(s1) * lc + sigf(s0) * tanhf(s2);
            const float lh = sigf(s3) * tanhf(lc);
            stc(lstm_hbuf + (size_t)(1 - par) * 65536 + (size_t)lrow * 512 + lghid, lh);
            lstm_out[((size_t)i * 128 + lrow) * 512 + lghid] = lh;
            __syncthreads();   // Ms reused below
        }

        // ----------------- Phase 1: GG + gates -> h ----------------------
        for (int s = tid; s < 4096; s += 256)
            Ms[(s >> 9) * 520 + (s & 511)] = ldc(Mbuf + pod * 4096 + s);
        __syncthreads();
        {
            const float* mrow = Ms + bq * 520;
            float a1 = 0.f, a2 = 0.f;
            for (int k = 0; k < 512; k += 4) {
                const float4 m4 = *(const float4*)(mrow + k);
                const float4 w4 = *(const float4*)(wrow1 + k);
                a1 += m4.x*w4.x + m4.y*w4.y + m4.z*w4.z + m4.w*w4.w;
                if (u < 16) {
                    const float4 v4 = *(const float4*)(wrow2 + k);
                    a2 += m4.x*v4.x + m4.y*v4.y + m4.z*v4.z + m4.w*v4.w;
                }
            }
            gg[bq * 48 + c1] = a1 + bia1;
            if (u < 16) gg[bq * 48 + c2] = a2 + bia2;
        }
        __syncthreads();
        if (tid < 64) {
            const int bb = tid >> 3, hc = tid & 7, j = J0 + hc;
            const int bgl = b0 + bb;
            const float g0v = gg[bb * 48 + hc];
            const float g1v = gg[bb * 48 + 8 + hc];
            const float g2v = gg[bb * 48 + 16 + hc];
            const float g3v = gg[bb * 48 + 24 + hc];
            const float g4v = gg[bb * 48 + 32 + hc];
            const float g5v = gg[bb * 48 + 40 + hc];
            const float mv  = Ms[bb * 520 + j];
            const float* pc = preQc + ((size_t)bgl * 128 + i) * 1536;
            const float* pp = preQp + ((size_t)bgl * 128 + i) * 1536;
            const float qv  = Hin[((size_t)bgl * 128 + i) * 512 + j];
            const float rc = sigf(pc[j] + g0v);
            const float zc = sigf(pc[512 + j] + g1v);
            const float nc = tanhf(pc[1024 + j] + rc * g2v);
            const float oc = (1.f - zc) * nc + zc * mv;
            const float rp = sigf(g3v + pp[j]);
            const float zp = sigf(g4v + pp[512 + j]);
            const float np = tanhf(g5v + rp * pp[1024 + j]);
            const float op = (1.f - zp) * np + zp * qv;
            const float h = oc + op;
            stc(hxch + pod * 4096 + bb * 512 + j, h);
            Hout[((size_t)bgl * 128 + i) * 512 + j] = h;
        }
        podbar(pbar, 64);

        // ----------------- Phase 2: hk, V, softmax, M' -------------------
        for (int s = tid; s < 4096; s += 256)
            Ms[(s >> 9) * 520 + (s & 511)] = ldc(hxch + pod * 4096 + s);
        __syncthreads();
        {   // hk partials (16-k chunks)
            const float* hr = Ms + bq * 520 + u * 16;
            const float* wkp = wkL + u * 16;
            float p = 0.f;
            #pragma unroll
            for (int kk = 0; kk < 16; ++kk) p += hr[kk] * wkp[kk];
            red[bq * 34 + u] = p;
        }
        __syncthreads();
        if (tid < 8) {
            float s = 0.f;
            for (int t2 = 0; t2 < 32; ++t2) s += red[tid * 34 + t2];
            eh[tid * 128 + i] = s;
        }
        __syncthreads();
        // V projection: 16 cols per WG (8 V0 + 8 V1), private history
        if (u < 16) {
            const float* wrow = (u < 8) ? Wr0 + (size_t)(J0 + u) * 512
                                        : Wr1 + (size_t)(J0 + u - 8) * 512;
            const float* hr = Ms + bq * 520;
            float v = 0.f;
            for (int k = 0; k < 512; k += 4) {
                const float4 h4 = *(const float4*)(hr + k);
                const float4 w4 = *(const float4*)(wrow + k);
                v += h4.x*w4.x + h4.y*w4.y + h4.z*w4.z + h4.w*w4.w;
            }
            Vh[(((size_t)wg * 8 + bq) * 128 + i) * 16 + u] = v;
        }
        if (i < 127) {
            const float* arow = adj + ((size_t)(b0 + bq) * 128 + (i + 1)) * 128;
            float amx = -3.0e38f;
            for (int n = u; n <= i; n += 32)
                amx = fmaxf(amx, eh[bq * 128 + n] - (1.f - arow[n]) * 1e30f);
            red[bq * 34 + u] = amx;
            __syncthreads();
            if (tid < 8) {
                float m = -3.0e38f;
                for (int t2 = 0; t2 < 32; ++t2) m = fmaxf(m, red[tid * 34 + t2]);
                red[tid * 34 + 32] = m;
            }
            __syncthreads();
            const float mxb = red[bq * 34 + 32];
            float es = 0.f;
            for (int n = u; n <= i; n += 32) {
                const float e = __expf(eh[bq * 128 + n] - (1.f - arow[n]) * 1e30f - mxb);
                wsf[bq * 128 + n] = e;
                es += e;
            }
            __syncthreads();
            red[bq * 34 + u] = es;
            __syncthreads();
            if (tid < 8) {
                float s = 0.f;
                for (int t2 = 0; t2 < 32; ++t2) s += red[tid * 34 + t2];
                red[tid * 34 + 33] = 1.f / s;
            }
            __syncthreads();
            if (tid < 64) {
                const int bb = tid >> 3, hc = tid & 7;
                const float invZ = red[bb * 34 + 33];
                const float* srow = smk + ((size_t)(b0 + bb) * 128 + (i + 1)) * 128;
                const float* vbase = Vh + (((size_t)wg * 8 + bb) * 128) * 16;
                float acc = 0.f;
                for (int n = 0; n <= i; ++n) {
                    const float wgt = wsf[bb * 128 + n];
                    const float v0 = vbase[n * 16 + hc];
                    const float v1 = vbase[n * 16 + 8 + hc];
                    acc += wgt * ((srow[n] != 0.f) ? v0 : v1);
                }
                stc(Mbuf + pod * 4096 + bb * 512 + J0 + hc, acc * invZ);
            }
        }
        podbar(pbar, 64);
    }
}

// ---------------------------------------------------------------------------
__global__ __launch_bounds__(256) void out_gemm(
    const float* __restrict__ x2, const float* __restrict__ W,
    const float* __restrict__ bias, float* __restrict__ out)
{
    __shared__ float xs[16 * 516];
    const int tid = threadIdx.x;
    const int r0 = blockIdx.x * 16;
    for (int idx = tid; idx < 16 * 512; idx += 256) {
        const int rr = idx >> 9, kk = idx & 511;
        xs[rr * 516 + kk] = x2[(size_t)(r0 + rr) * 512 + kk];
    }
    __syncthreads();
    if (tid < 128) {
        const int r = tid >> 3, c = tid & 7;
        if (c < 7) {
            float acc = bias[c];
            const float* wr = W + c * 512;
            const float* xr = xs + r * 516;
            for (int k = 0; k < 512; ++k) acc += xr[k] * wr[k];
            out[(size_t)(r0 + r) * 7 + c] = acc;
        }
    }
}

// ---------------------------------------------------------------------------
extern "C" void kernel_launch(void* const* d_in, const int* in_sizes, int n_in,
                              void* d_out, int out_size, void* d_ws, size_t ws_size,
                              hipStream_t stream) {
    (void)in_sizes; (void)n_in; (void)out_size; (void)ws_size;
    const float* feat     = (const float*)d_in[0];
    const float* adj      = (const float*)d_in[1];
    const float* smask    = (const float*)d_in[2];
    const float* lstm_Wih = (const float*)d_in[5];
    const float* lstm_Whh = (const float*)d_in[6];
    const float* lstm_bih = (const float*)d_in[7];
    const float* lstm_bhh = (const float*)d_in[8];
    const float* fc1_W    = (const float*)d_in[9];
    const float* fc1_b    = (const float*)d_in[10];
    const float* attn_W   = (const float*)d_in[11];
    const float* attn_b   = (const float*)d_in[12];  // cancels in softmax
    (void)attn_b;
    const float* Wr0      = (const float*)d_in[13];
    const float* Wr1      = (const float*)d_in[14];
    const float* gruC_Wih = (const float*)d_in[15];
    const float* gruC_Whh = (const float*)d_in[16];
    const float* gruC_bih = (const float*)d_in[17];
    const float* gruC_bhh = (const float*)d_in[18];
    const float* gruP_Wih = (const float*)d_in[19];
    const float* gruP_Whh = (const float*)d_in[20];
    const float* gruP_bih = (const float*)d_in[21];
    const float* gruP_bhh = (const float*)d_in[22];
    const float* mlp0_W   = (const float*)d_in[23];
    const float* mlp0_b   = (const float*)d_in[24];
    const float* mlp1_W   = (const float*)d_in[25];
    const float* mlp1_b   = (const float*)d_in[26];
    const float* out_W    = (const float*)d_in[27];
    const float* out_b    = (const float*)d_in[28];

    float* ws       = (float*)d_ws;
    float* lstm_gi  = ws;                       // 8,388,608
    float* lstm_out = lstm_gi + 8388608;        // 2,097,152
    float* H0       = lstm_out + 2097152;       // 2,097,152
    float* H1       = H0 + 2097152;             // 2,097,152
    float* H2       = H1 + 2097152;             // 2,097,152
    float* preQc    = H2 + 2097152;             // 6,291,456
    float* preQp    = preQc + 6291456;          // 6,291,456
    float* x1       = preQp + 6291456;          // 2,097,152
    float* x2       = x1 + 2097152;             // 2,097,152
    float* Mbuf     = x2 + 2097152;             // 16,384  [pod][8][512]
    float* hxch     = Mbuf + 16384;             // 16,384  [pod][8][512]
    float* Vh       = hxch + 16384;             // 4,194,304 [wg][8][128][16]
    float* lstm_hb  = Vh + 4194304;             // 131,072 [2][128][512]
    int*   bar      = (int*)(lstm_hb + 131072); // 1,024 ints

    const dim3 blk(256);
    init_bar<<<1, 1024, 0, stream>>>(bar);

    // parallel-phase GEMMs
    gemm_nt<<<dim3(64, 8), blk, 0, stream>>>(feat, fc1_W, fc1_b, H0, 4096, 512, 1024, 1);
    gemm_nt<<<dim3(64, 32), blk, 0, stream>>>(feat, lstm_Wih, lstm_bih, lstm_gi, 4096, 2048, 1024, 0);
    gemm_nt<<<dim3(64, 24), blk, 0, stream>>>(H0, gruC_Wih, gruC_bih, preQc, 4096, 1536, 512, 0);
    gemm_nt<<<dim3(64, 24), blk, 0, stream>>>(H0, gruP_Whh, gruP_bhh, preQp, 4096, 1536, 512, 0);

    // layer 0 scan (+ LSTM folded into first 32 steps)
    scan_layer<<<256, blk, 0, stream>>>(
        H0, H1, adj, smask, preQc, preQp,
        gruC_Whh, gruP_Wih, gruC_bhh, gruP_bih, attn_W,
        Wr0, Wr1, Mbuf, hxch, Vh, bar, 1,
        lstm_gi, lstm_Whh, lstm_bhh, lstm_hb, lstm_out);

    // layer-1 preQ
    gemm_nt<<<dim3(64, 24), blk, 0, stream>>>(H1, gruC_Wih + (size_t)1536 * 512,
                                              gruC_bih + 1536, preQc, 4096, 1536, 512, 0);
    gemm_nt<<<dim3(64, 24), blk, 0, stream>>>(H1, gruP_Whh + (size_t)1536 * 512,
                                              gruP_bhh + 1536, preQp, 4096, 1536, 512, 0);

    // layer 1 scan
    scan_layer<<<256, blk, 0, stream>>>(
        H1, H2, adj, smask, preQc, preQp,
        gruC_Whh + (size_t)1536 * 512, gruP_Wih + (size_t)1536 * 512,
        gruC_bhh + 1536, gruP_bih + 1536, attn_W + 1024,
        Wr0 + (size_t)512 * 512, Wr1 + (size_t)512 * 512,
        Mbuf, hxch, Vh, bar, 0,
        lstm_gi, lstm_Whh, lstm_bhh, lstm_hb, lstm_out);

    // head
    gemm_cat<<<dim3(64, 8), blk, 0, stream>>>(H0, H1, H2, feat, lstm_out, mlp0_W, mlp0_b, x1);
    gemm_nt<<<dim3(64, 8), blk, 0, stream>>>(x1, mlp1_W, mlp1_b, x2, 4096, 512, 512, 1);
    out_gemm<<<256, blk, 0, stream>>>(x2, out_W, out_b, (float*)d_out);
}